// Round 4
// baseline (1565.651 us; speedup 1.0000x reference)
//
#include <hip/hip_runtime.h>

// SAGEConv: out = h@W_self.T + b_self + b_nb + segsum(val * (h@W_nb.T)[col])
// R4: kill scatter_csr's 8x write amplification (100MB for 12.8MB payload,
// 125us) via 256-row buckets: LDS counting-sort write-combined scatter
// (coalesced run flushes) + per-bucket LDS fp32 accumulator aggregation.
// Also deletes the 100K-row histogram/scan pipeline (replaced by capacity-
// strided bucket regions + per-bucket atomic cursors).

constexpr int NN = 100000;
constexpr int NE = 1600000;
constexpr int D  = 128;
constexpr int NN_PAD = 100032;             // 64-row padded for GEMM tiles
constexpr int NBUCK  = 391;                // ceil(NN/256) buckets of 256 rows
constexpr int BCAP   = 4608;               // per-bucket capacity: mean 4096 + 8 sigma
constexpr int CHUNK  = 4096;               // edges per wc_scatter workgroup
constexpr int NCH    = (NE + CHUNK - 1) / CHUNK;   // 391

typedef __bf16 bf16x8 __attribute__((ext_vector_type(8)));
typedef float  f32x4  __attribute__((ext_vector_type(4)));

// ---------------- W concat -> bf16 table wcat[256][128] ----------------
__global__ __launch_bounds__(256) void w_convert(
    const float* __restrict__ Wself, const float* __restrict__ Wnb,
    __bf16* __restrict__ wcat) {
    int i = blockIdx.x * 256 + threadIdx.x;   // 0..32767
    int n = i >> 7, k = i & 127;
    float v = (n < D) ? Wself[(size_t)n * D + k] : Wnb[(size_t)(n - D) * D + k];
    wcat[i] = (__bf16)v;
}

// ---------------- Dual GEMM, LDS-free MFMA (unchanged from R3) ----------
__global__ __launch_bounds__(256) void gemm_mfma(
    const float* __restrict__ h,
    const __bf16* __restrict__ wcat,
    const float* __restrict__ bself,
    const float* __restrict__ bnb,
    float* __restrict__ out,
    __bf16* __restrict__ tmpb)
{
    const int t    = threadIdx.x;
    const int wv   = t >> 6;
    const int lane = t & 63;
    const int l15  = lane & 15;
    const int quad = lane >> 4;
    const int m0   = blockIdx.x * 64 + wv * 16;

    int arow = m0 + l15;
    if (arow >= NN) arow = NN - 1;
    const float* aptr = h + (size_t)arow * D + quad * 8;

    bf16x8 afr[4];
    #pragma unroll
    for (int kk = 0; kk < 4; ++kk) {
        f32x4 lo = *(const f32x4*)(aptr + kk * 32);
        f32x4 hi = *(const f32x4*)(aptr + kk * 32 + 4);
        bf16x8 a;
        #pragma unroll
        for (int j = 0; j < 4; ++j) { a[j] = (__bf16)lo[j]; a[4 + j] = (__bf16)hi[j]; }
        afr[kk] = a;
    }

    f32x4 acc[16];
    #pragma unroll
    for (int ns = 0; ns < 16; ++ns) acc[ns] = (f32x4){0.f, 0.f, 0.f, 0.f};

    #pragma unroll
    for (int ns = 0; ns < 16; ++ns) {
        const __bf16* wr = wcat + (size_t)(ns * 16 + l15) * D + quad * 8;
        #pragma unroll
        for (int kk = 0; kk < 4; ++kk) {
            bf16x8 b = *(const bf16x8*)(wr + kk * 32);
            acc[ns] = __builtin_amdgcn_mfma_f32_16x16x32_bf16(afr[kk], b, acc[ns], 0, 0, 0);
        }
    }

    #pragma unroll
    for (int ns = 0; ns < 16; ++ns) {
        int col = ns * 16 + l15;
        float bias = (col < D) ? (bself[col] + bnb[col]) : 0.f;
        #pragma unroll
        for (int i = 0; i < 4; ++i) {
            int row = m0 + quad * 4 + i;
            if (row < NN) {
                float v = acc[ns][i];
                if (col < D) out[(size_t)row * D + col] = v + bias;
                else         tmpb[(size_t)row * D + (col - D)] = (__bf16)v;
            }
        }
    }
}

// ---------------- Write-combined bucket scatter ----------------
// Each WG: 4096 edges -> LDS counting-sort by bucket (row>>8) -> claim global
// run per bucket via one atomicAdd(gcount[b], runlen) -> coalesced run flush.
__global__ __launch_bounds__(256) void wc_scatter(
    const int* __restrict__ erow, const int* __restrict__ ecol,
    const float* __restrict__ eval_,
    int* __restrict__ gcount, int2* __restrict__ epair)
{
    __shared__ int  cnt[NBUCK];
    __shared__ int  lscan[NBUCK];
    __shared__ int  gbase[NBUCK];
    __shared__ int  ss[512];
    __shared__ int2 sbuf[CHUNK];
    __shared__ int  saddr[CHUNK];
    __shared__ int  s_total;

    const int t  = threadIdx.x;
    const int c0 = blockIdx.x * CHUNK;

    for (int b = t; b < NBUCK; b += 256) cnt[b] = 0;
    __syncthreads();

    // Phase A: read 16 edges/thread (coalesced), LDS-histogram, keep regs.
    int   bp[16];      // b | rlo<<9 | pos<<17  (or -1 if OOB)
    int   colr[16];
    float valr[16];
    #pragma unroll
    for (int j = 0; j < 16; ++j) {
        int e = c0 + j * 256 + t;
        if (e < NE) {
            int r   = erow[e];
            colr[j] = ecol[e];
            valr[j] = eval_[e];
            int b   = r >> 8;
            int pos = atomicAdd(&cnt[b], 1);
            bp[j]   = b | ((r & 255) << 9) | (pos << 17);
        } else bp[j] = -1;
    }
    __syncthreads();

    // Phase B: in-LDS inclusive scan of cnt (padded to 512, 2 elems/thread).
    ss[t]       = (t < NBUCK)       ? cnt[t]       : 0;
    ss[t + 256] = (t + 256 < NBUCK) ? cnt[t + 256] : 0;
    __syncthreads();
    for (int off = 1; off < 512; off <<= 1) {
        int i0 = t, i1 = t + 256;
        int r0 = ss[i0] + ((i0 >= off) ? ss[i0 - off] : 0);
        int r1 = ss[i1] + ((i1 >= off) ? ss[i1 - off] : 0);
        __syncthreads();
        ss[i0] = r0; ss[i1] = r1;
        __syncthreads();
    }
    // Phase C: exclusive scan + global run bases.
    if (t < NBUCK) {
        int n = cnt[t];
        lscan[t] = ss[t] - n;
        gbase[t] = (n > 0) ? atomicAdd(&gcount[t], n) : 0;
    }
    if (t + 256 < NBUCK) {
        int n = cnt[t + 256];
        lscan[t + 256] = ss[t + 256] - n;
        gbase[t + 256] = (n > 0) ? atomicAdd(&gcount[t + 256], n) : 0;
    }
    if (t == 0) s_total = ss[511];
    __syncthreads();

    // Phase D: place sorted pairs + their global destinations in LDS.
    #pragma unroll
    for (int j = 0; j < 16; ++j) {
        if (bp[j] >= 0) {
            int b   = bp[j] & 511;
            int rlo = (bp[j] >> 9) & 255;
            int pos = bp[j] >> 17;
            int slot = lscan[b] + pos;
            sbuf[slot]  = make_int2(colr[j] | (rlo << 17), __float_as_int(valr[j]));
            saddr[slot] = b * BCAP + gbase[b] + pos;
        }
    }
    __syncthreads();

    // Phase E: coalesced flush (consecutive slots -> consecutive addresses
    // within each run; runs avg ~10.5 pairs -> mostly full 64B lines).
    int ce = s_total;
    for (int i = t; i < ce; i += 256)
        epair[saddr[i]] = sbuf[i];
}

// ---------------- Aggregate: one WG per bucket, LDS fp32 accumulator ----
__global__ __launch_bounds__(256) void bucket_aggregate(
    const __bf16* __restrict__ tmpb, const int* __restrict__ gcount,
    const int2* __restrict__ epair, float* __restrict__ out)
{
    __shared__ float acc[256][D];   // 128 KB
    const int t = threadIdx.x;
    const int b = blockIdx.x;

    f32x4* az = (f32x4*)&acc[0][0];
    for (int i = t; i < 8192; i += 256) az[i] = (f32x4){0.f, 0.f, 0.f, 0.f};
    __syncthreads();

    const int n = gcount[b];
    const int2* ep = epair + (size_t)b * BCAP;
    const int wv = t >> 6, lane = t & 63;
    const int per = (n + 3) >> 2;
    const int beg = wv * per;
    const int end = min(n, beg + per);

    // 8-deep unroll: 8 independent gathers in flight per wave.
    for (int e = beg; e < end; e += 8) {
        int2 p[8];
        #pragma unroll
        for (int k = 0; k < 8; ++k) p[k] = ep[min(e + k, end - 1)];
        unsigned u[8];
        #pragma unroll
        for (int k = 0; k < 8; ++k) {
            int col = p[k].x & 0x1FFFF;
            u[k] = *(const unsigned*)(tmpb + (size_t)col * D + lane * 2);
        }
        #pragma unroll
        for (int k = 0; k < 8; ++k) {
            if (e + k < end) {
                int   rlo = p[k].x >> 17;
                float v   = __int_as_float(p[k].y);
                float x0  = __uint_as_float(u[k] << 16);
                float x1  = __uint_as_float(u[k] & 0xffff0000u);
                atomicAdd(&acc[rlo][lane * 2],     v * x0);
                atomicAdd(&acc[rlo][lane * 2 + 1], v * x1);
            }
        }
    }
    __syncthreads();

    // Dense epilogue: out rows [b*256, b*256+256) += acc.
    const int row0 = b * 256;
    for (int i = t; i < 8192; i += 256) {
        int rlo = i >> 5, c4 = (i & 31) * 4;
        int row = row0 + rlo;
        if (row < NN) {
            f32x4* op = (f32x4*)(out + (size_t)row * D + c4);
            f32x4 cur = *op;
            f32x4 a = *(f32x4*)&acc[rlo][c4];
            cur += a;
            *op = cur;
        }
    }
}

extern "C" void kernel_launch(void* const* d_in, const int* in_sizes, int n_in,
                              void* d_out, int out_size, void* d_ws, size_t ws_size,
                              hipStream_t stream) {
    const float* h     = (const float*)d_in[0];
    const float* eval_ = (const float*)d_in[1];
    const float* Wself = (const float*)d_in[2];
    const float* bself = (const float*)d_in[3];
    const float* Wnb   = (const float*)d_in[4];
    const float* bnb   = (const float*)d_in[5];
    const int*   erow  = (const int*)d_in[6];
    const int*   ecol  = (const int*)d_in[7];
    float* out = (float*)d_out;

    // ws layout: tmpb 25.6MB | epair 14.4MB | wcat 64KB | gcount 1.6KB
    char* p = (char*)d_ws;
    __bf16* tmpb  = (__bf16*)p;     p += (size_t)NN_PAD * D * 2;
    int2*   epair = (int2*)p;       p += (size_t)NBUCK * BCAP * 8;
    __bf16* wcat  = (__bf16*)p;     p += 256 * 128 * 2;
    int*    gcount = (int*)p;

    hipMemsetAsync(gcount, 0, NBUCK * 4, stream);

    w_convert<<<128, 256, 0, stream>>>(Wself, Wnb, wcat);
    gemm_mfma<<<NN_PAD / 64, 256, 0, stream>>>(h, wcat, bself, bnb, out, tmpb);
    wc_scatter<<<NCH, 256, 0, stream>>>(erow, ecol, eval_, gcount, epair);
    bucket_aggregate<<<NBUCK, 256, 0, stream>>>(tmpb, gcount, epair, out);
}

// Round 5
// 288.809 us; speedup vs baseline: 5.4211x; 5.4211x over previous
//
#include <hip/hip_runtime.h>

// SAGEConv: out = h@W_self.T + b_self + b_nb + segsum(val * (h@W_nb.T)[col])
// R5: wc_scatter (R4, write-combined bucket scatter, ~25MB writes vs 100MB
// line-granular) + bucket_sort (rows within bucket, 41KB LDS, 4 blk/CU)
// + R3's TLP-rich wave-per-row aggregate (100K waves). Deletes histogram +
// 3-kernel scan + scatter_csr. R4's 128KB-LDS bucket_aggregate (1 blk/CU,
// latency-bound, 1376us) is gone.

constexpr int NN = 100000;
constexpr int NE = 1600000;
constexpr int D  = 128;
constexpr int NN_PAD = 100032;             // 64-row padded for GEMM tiles
constexpr int NBUCK  = 391;                // ceil(NN/256) buckets of 256 rows
constexpr int BCAP   = 4608;               // mean 4096 + 8 sigma
constexpr int CHUNK  = 4096;               // edges per wc_scatter workgroup
constexpr int NCH    = (NE + CHUNK - 1) / CHUNK;   // 391

typedef __bf16 bf16x8 __attribute__((ext_vector_type(8)));
typedef float  f32x4  __attribute__((ext_vector_type(4)));

// ---------------- W concat -> bf16 table wcat[256][128] ----------------
__global__ __launch_bounds__(256) void w_convert(
    const float* __restrict__ Wself, const float* __restrict__ Wnb,
    __bf16* __restrict__ wcat) {
    int i = blockIdx.x * 256 + threadIdx.x;   // 0..32767
    int n = i >> 7, k = i & 127;
    float v = (n < D) ? Wself[(size_t)n * D + k] : Wnb[(size_t)(n - D) * D + k];
    wcat[i] = (__bf16)v;
}

// ---------------- Dual GEMM, LDS-free MFMA (unchanged, proven) ----------
__global__ __launch_bounds__(256) void gemm_mfma(
    const float* __restrict__ h,
    const __bf16* __restrict__ wcat,
    const float* __restrict__ bself,
    const float* __restrict__ bnb,
    float* __restrict__ out,
    __bf16* __restrict__ tmpb)
{
    const int t    = threadIdx.x;
    const int wv   = t >> 6;
    const int lane = t & 63;
    const int l15  = lane & 15;
    const int quad = lane >> 4;
    const int m0   = blockIdx.x * 64 + wv * 16;

    int arow = m0 + l15;
    if (arow >= NN) arow = NN - 1;
    const float* aptr = h + (size_t)arow * D + quad * 8;

    bf16x8 afr[4];
    #pragma unroll
    for (int kk = 0; kk < 4; ++kk) {
        f32x4 lo = *(const f32x4*)(aptr + kk * 32);
        f32x4 hi = *(const f32x4*)(aptr + kk * 32 + 4);
        bf16x8 a;
        #pragma unroll
        for (int j = 0; j < 4; ++j) { a[j] = (__bf16)lo[j]; a[4 + j] = (__bf16)hi[j]; }
        afr[kk] = a;
    }

    f32x4 acc[16];
    #pragma unroll
    for (int ns = 0; ns < 16; ++ns) acc[ns] = (f32x4){0.f, 0.f, 0.f, 0.f};

    #pragma unroll
    for (int ns = 0; ns < 16; ++ns) {
        const __bf16* wr = wcat + (size_t)(ns * 16 + l15) * D + quad * 8;
        #pragma unroll
        for (int kk = 0; kk < 4; ++kk) {
            bf16x8 b = *(const bf16x8*)(wr + kk * 32);
            acc[ns] = __builtin_amdgcn_mfma_f32_16x16x32_bf16(afr[kk], b, acc[ns], 0, 0, 0);
        }
    }

    #pragma unroll
    for (int ns = 0; ns < 16; ++ns) {
        int col = ns * 16 + l15;
        float bias = (col < D) ? (bself[col] + bnb[col]) : 0.f;
        #pragma unroll
        for (int i = 0; i < 4; ++i) {
            int row = m0 + quad * 4 + i;
            if (row < NN) {
                float v = acc[ns][i];
                if (col < D) out[(size_t)row * D + col] = v + bias;
                else         tmpb[(size_t)row * D + (col - D)] = (__bf16)v;
            }
        }
    }
}

// ---------------- Write-combined bucket scatter (unchanged from R4) -----
__global__ __launch_bounds__(256) void wc_scatter(
    const int* __restrict__ erow, const int* __restrict__ ecol,
    const float* __restrict__ eval_,
    int* __restrict__ gcount, int2* __restrict__ epair)
{
    __shared__ int  cnt[NBUCK];
    __shared__ int  lscan[NBUCK];
    __shared__ int  gbase[NBUCK];
    __shared__ int  ss[512];
    __shared__ int2 sbuf[CHUNK];
    __shared__ int  saddr[CHUNK];
    __shared__ int  s_total;

    const int t  = threadIdx.x;
    const int c0 = blockIdx.x * CHUNK;

    for (int b = t; b < NBUCK; b += 256) cnt[b] = 0;
    __syncthreads();

    int   bp[16];      // b | rlo<<9 | pos<<17  (or -1 if OOB)
    int   colr[16];
    float valr[16];
    #pragma unroll
    for (int j = 0; j < 16; ++j) {
        int e = c0 + j * 256 + t;
        if (e < NE) {
            int r   = erow[e];
            colr[j] = ecol[e];
            valr[j] = eval_[e];
            int b   = r >> 8;
            int pos = atomicAdd(&cnt[b], 1);
            bp[j]   = b | ((r & 255) << 9) | (pos << 17);
        } else bp[j] = -1;
    }
    __syncthreads();

    ss[t]       = (t < NBUCK)       ? cnt[t]       : 0;
    ss[t + 256] = (t + 256 < NBUCK) ? cnt[t + 256] : 0;
    __syncthreads();
    for (int off = 1; off < 512; off <<= 1) {
        int i0 = t, i1 = t + 256;
        int r0 = ss[i0] + ((i0 >= off) ? ss[i0 - off] : 0);
        int r1 = ss[i1] + ((i1 >= off) ? ss[i1 - off] : 0);
        __syncthreads();
        ss[i0] = r0; ss[i1] = r1;
        __syncthreads();
    }
    if (t < NBUCK) {
        int n = cnt[t];
        lscan[t] = ss[t] - n;
        gbase[t] = (n > 0) ? atomicAdd(&gcount[t], n) : 0;
    }
    if (t + 256 < NBUCK) {
        int n = cnt[t + 256];
        lscan[t + 256] = ss[t + 256] - n;
        gbase[t + 256] = (n > 0) ? atomicAdd(&gcount[t + 256], n) : 0;
    }
    if (t == 0) s_total = ss[511];
    __syncthreads();

    #pragma unroll
    for (int j = 0; j < 16; ++j) {
        if (bp[j] >= 0) {
            int b   = bp[j] & 511;
            int rlo = (bp[j] >> 9) & 255;
            int pos = bp[j] >> 17;
            int slot = lscan[b] + pos;
            sbuf[slot]  = make_int2(colr[j] | (rlo << 17), __float_as_int(valr[j]));
            saddr[slot] = b * BCAP + gbase[b] + pos;
        }
    }
    __syncthreads();

    int ce = s_total;
    for (int i = t; i < ce; i += 256)
        epair[saddr[i]] = sbuf[i];
}

// ---------------- Bucket sort: rows within bucket, emit row ranges ------
// One block per bucket; counting-sort <=4608 pairs by rlo in 41KB LDS.
__global__ __launch_bounds__(256) void bucket_sort(
    const int2* __restrict__ epair, const int* __restrict__ gcount,
    int2* __restrict__ epair2, int2* __restrict__ rowrange)
{
    __shared__ int  cnt[256];
    __shared__ int  off[256];
    __shared__ int  cur[256];
    __shared__ int  ss[256];
    __shared__ int2 sorted[BCAP];

    const int t = threadIdx.x;
    const int b = blockIdx.x;
    const int n = gcount[b];
    const int2* src = epair + (size_t)b * BCAP;

    cnt[t] = 0;
    __syncthreads();
    for (int i = t; i < n; i += 256)
        atomicAdd(&cnt[(src[i].x >> 17) & 255], 1);
    __syncthreads();

    int v = cnt[t];
    ss[t] = v;
    __syncthreads();
    for (int o = 1; o < 256; o <<= 1) {
        int y = (t >= o) ? ss[t - o] : 0;
        __syncthreads();
        ss[t] += y;
        __syncthreads();
    }
    off[t] = ss[t] - v;
    cur[t] = ss[t] - v;
    __syncthreads();

    for (int i = t; i < n; i += 256) {
        int2 p = src[i];
        int slot = atomicAdd(&cur[(p.x >> 17) & 255], 1);
        sorted[slot] = p;
    }
    __syncthreads();

    const int base = b * BCAP;
    for (int i = t; i < n; i += 256)
        epair2[base + i] = sorted[i];
    int row = b * 256 + t;
    if (row < NN)
        rowrange[row] = make_int2(base + off[t], base + off[t] + cnt[t]);
}

// ---------------- Aggregate: one wave per row (TLP-rich), 4x unroll -----
__global__ __launch_bounds__(256) void aggregate(
    const __bf16* __restrict__ tmpb, const int2* __restrict__ rowrange,
    const int2* __restrict__ epair2, float* __restrict__ out)
{
    int wave = (blockIdx.x * 256 + threadIdx.x) >> 6;
    if (wave >= NN) return;
    int lane = threadIdx.x & 63;
    int2 rr = rowrange[wave];
    int beg = rr.x, end = rr.y;

    float ax[4] = {0.f, 0.f, 0.f, 0.f};
    float ay[4] = {0.f, 0.f, 0.f, 0.f};
    int e = beg;
    for (; e + 3 < end; e += 4) {
        int2 p[4];
        #pragma unroll
        for (int k = 0; k < 4; ++k) p[k] = epair2[e + k];
        #pragma unroll
        for (int k = 0; k < 4; ++k) {
            int col = p[k].x & 0x1FFFF;
            unsigned u = *(const unsigned*)(tmpb + (size_t)col * D + lane * 2);
            float v = __int_as_float(p[k].y);
            ax[k] += v * __uint_as_float(u << 16);
            ay[k] += v * __uint_as_float(u & 0xffff0000u);
        }
    }
    for (; e < end; ++e) {
        int2 p = epair2[e];
        int col = p.x & 0x1FFFF;
        unsigned u = *(const unsigned*)(tmpb + (size_t)col * D + lane * 2);
        float v = __int_as_float(p.y);
        ax[0] += v * __uint_as_float(u << 16);
        ay[0] += v * __uint_as_float(u & 0xffff0000u);
    }
    float2* o = (float2*)(out + (size_t)wave * D + lane * 2);
    float2 c = *o;
    c.x += (ax[0] + ax[1]) + (ax[2] + ax[3]);
    c.y += (ay[0] + ay[1]) + (ay[2] + ay[3]);
    *o = c;
}

extern "C" void kernel_launch(void* const* d_in, const int* in_sizes, int n_in,
                              void* d_out, int out_size, void* d_ws, size_t ws_size,
                              hipStream_t stream) {
    const float* h     = (const float*)d_in[0];
    const float* eval_ = (const float*)d_in[1];
    const float* Wself = (const float*)d_in[2];
    const float* bself = (const float*)d_in[3];
    const float* Wnb   = (const float*)d_in[4];
    const float* bnb   = (const float*)d_in[5];
    const int*   erow  = (const int*)d_in[6];
    const int*   ecol  = (const int*)d_in[7];
    float* out = (float*)d_out;

    // ws: tmpb 25.6MB | epair 14.4MB | epair2 14.4MB | rowrange 800KB
    //     | wcat 64KB | gcount 1.6KB  -> ~55.3MB
    char* p = (char*)d_ws;
    __bf16* tmpb    = (__bf16*)p;   p += (size_t)NN_PAD * D * 2;
    int2*   epair   = (int2*)p;     p += (size_t)NBUCK * BCAP * 8;
    int2*   epair2  = (int2*)p;     p += (size_t)NBUCK * BCAP * 8;
    int2*   rowrange= (int2*)p;     p += (size_t)NN * 8;
    __bf16* wcat    = (__bf16*)p;   p += 256 * 128 * 2;
    int*    gcount  = (int*)p;

    hipMemsetAsync(gcount, 0, NBUCK * 4, stream);

    w_convert<<<128, 256, 0, stream>>>(Wself, Wnb, wcat);
    gemm_mfma<<<NN_PAD / 64, 256, 0, stream>>>(h, wcat, bself, bnb, out, tmpb);
    wc_scatter<<<NCH, 256, 0, stream>>>(erow, ecol, eval_, gcount, epair);
    bucket_sort<<<NBUCK, 256, 0, stream>>>(epair, gcount, epair2, rowrange);
    aggregate<<<(NN * 64) / 256, 256, 0, stream>>>(tmpb, rowrange, epair2, out);
}

// Round 6
// 284.690 us; speedup vs baseline: 5.4995x; 1.0145x over previous
//
#include <hip/hip_runtime.h>

// SAGEConv: out = h@W_self.T + b_self + b_nb + segsum(val * (h@W_nb.T)[col])
// R6: (a) gemm_mfma restructured: B register-resident (N-split across waves,
//     16 frags = 64 VGPRs loaded once, amortized over 4 M-chunks) — kills the
//     L2-latency-bound per-MFMA B loads (was MfmaUtil 3%, 78us).
//     (b) aggregate: 8-deep gather unroll for more MLP (was 42% HBM).

constexpr int NN = 100000;
constexpr int NE = 1600000;
constexpr int D  = 128;
constexpr int NN_PAD = 100032;             // 64-row padded for GEMM tiles
constexpr int NBUCK  = 391;                // ceil(NN/256) buckets of 256 rows
constexpr int BCAP   = 4608;               // mean 4096 + 8 sigma
constexpr int CHUNK  = 4096;               // edges per wc_scatter workgroup
constexpr int NCH    = (NE + CHUNK - 1) / CHUNK;   // 391

typedef __bf16 bf16x8 __attribute__((ext_vector_type(8)));
typedef float  f32x4  __attribute__((ext_vector_type(4)));

// ---------------- W concat -> bf16 table wcat[256][128] ----------------
__global__ __launch_bounds__(256) void w_convert(
    const float* __restrict__ Wself, const float* __restrict__ Wnb,
    __bf16* __restrict__ wcat) {
    int i = blockIdx.x * 256 + threadIdx.x;   // 0..32767
    int n = i >> 7, k = i & 127;
    float v = (n < D) ? Wself[(size_t)n * D + k] : Wnb[(size_t)(n - D) * D + k];
    wcat[i] = (__bf16)v;
}

// ---------------- Dual GEMM: register-resident B, N-split across waves --
// Block: 64 rows x 256 cols. Wave w owns col panel [w*64, w*64+64):
// preload 16 B frags (64 VGPRs) once; loop 4 chunks of 16 rows.
__global__ __launch_bounds__(256) void gemm_mfma(
    const float* __restrict__ h,
    const __bf16* __restrict__ wcat,
    const float* __restrict__ bself,
    const float* __restrict__ bnb,
    float* __restrict__ out,
    __bf16* __restrict__ tmpb)
{
    const int t    = threadIdx.x;
    const int w    = t >> 6;          // wave id = col panel
    const int lane = t & 63;
    const int l15  = lane & 15;
    const int quad = lane >> 4;

    // Preload B frags: b[ns][kk], frag elem k = quad*8 + kk*32 + j.
    bf16x8 b[4][4];
    #pragma unroll
    for (int ns = 0; ns < 4; ++ns) {
        const __bf16* wb = wcat + (size_t)(w * 64 + ns * 16 + l15) * D + quad * 8;
        #pragma unroll
        for (int kk = 0; kk < 4; ++kk)
            b[ns][kk] = *(const bf16x8*)(wb + kk * 32);
    }

    // Bias per ns (only meaningful for col panels 0,1 -> cols < 128).
    float bias[4];
    #pragma unroll
    for (int ns = 0; ns < 4; ++ns) {
        int col = w * 64 + ns * 16 + l15;
        bias[ns] = (col < D) ? (bself[col] + bnb[col]) : 0.f;
    }

    #pragma unroll
    for (int c = 0; c < 4; ++c) {
        const int m0 = blockIdx.x * 64 + c * 16;
        int arow = m0 + l15;
        if (arow >= NN) arow = NN - 1;
        const float* aptr = h + (size_t)arow * D + quad * 8;

        bf16x8 afr[4];
        #pragma unroll
        for (int kk = 0; kk < 4; ++kk) {
            f32x4 lo = *(const f32x4*)(aptr + kk * 32);
            f32x4 hi = *(const f32x4*)(aptr + kk * 32 + 4);
            bf16x8 a;
            #pragma unroll
            for (int j = 0; j < 4; ++j) { a[j] = (__bf16)lo[j]; a[4 + j] = (__bf16)hi[j]; }
            afr[kk] = a;
        }

        f32x4 acc[4];
        #pragma unroll
        for (int ns = 0; ns < 4; ++ns) acc[ns] = (f32x4){0.f, 0.f, 0.f, 0.f};
        #pragma unroll
        for (int ns = 0; ns < 4; ++ns)
            #pragma unroll
            for (int kk = 0; kk < 4; ++kk)
                acc[ns] = __builtin_amdgcn_mfma_f32_16x16x32_bf16(afr[kk], b[ns][kk], acc[ns], 0, 0, 0);

        // Epilogue. C/D layout: col=lane&15 (within subtile), row=quad*4+i.
        if (w < 2) {
            #pragma unroll
            for (int ns = 0; ns < 4; ++ns) {
                int col = w * 64 + ns * 16 + l15;
                #pragma unroll
                for (int i = 0; i < 4; ++i) {
                    int row = m0 + quad * 4 + i;
                    if (row < NN) out[(size_t)row * D + col] = acc[ns][i] + bias[ns];
                }
            }
        } else {
            #pragma unroll
            for (int ns = 0; ns < 4; ++ns) {
                int col = w * 64 + ns * 16 + l15 - D;
                #pragma unroll
                for (int i = 0; i < 4; ++i) {
                    int row = m0 + quad * 4 + i;
                    if (row < NN) tmpb[(size_t)row * D + col] = (__bf16)acc[ns][i];
                }
            }
        }
    }
}

// ---------------- Write-combined bucket scatter (unchanged) -------------
__global__ __launch_bounds__(256) void wc_scatter(
    const int* __restrict__ erow, const int* __restrict__ ecol,
    const float* __restrict__ eval_,
    int* __restrict__ gcount, int2* __restrict__ epair)
{
    __shared__ int  cnt[NBUCK];
    __shared__ int  lscan[NBUCK];
    __shared__ int  gbase[NBUCK];
    __shared__ int  ss[512];
    __shared__ int2 sbuf[CHUNK];
    __shared__ int  saddr[CHUNK];
    __shared__ int  s_total;

    const int t  = threadIdx.x;
    const int c0 = blockIdx.x * CHUNK;

    for (int b = t; b < NBUCK; b += 256) cnt[b] = 0;
    __syncthreads();

    int   bp[16];      // b | rlo<<9 | pos<<17  (or -1 if OOB)
    int   colr[16];
    float valr[16];
    #pragma unroll
    for (int j = 0; j < 16; ++j) {
        int e = c0 + j * 256 + t;
        if (e < NE) {
            int r   = erow[e];
            colr[j] = ecol[e];
            valr[j] = eval_[e];
            int b   = r >> 8;
            int pos = atomicAdd(&cnt[b], 1);
            bp[j]   = b | ((r & 255) << 9) | (pos << 17);
        } else bp[j] = -1;
    }
    __syncthreads();

    ss[t]       = (t < NBUCK)       ? cnt[t]       : 0;
    ss[t + 256] = (t + 256 < NBUCK) ? cnt[t + 256] : 0;
    __syncthreads();
    for (int off = 1; off < 512; off <<= 1) {
        int i0 = t, i1 = t + 256;
        int r0 = ss[i0] + ((i0 >= off) ? ss[i0 - off] : 0);
        int r1 = ss[i1] + ((i1 >= off) ? ss[i1 - off] : 0);
        __syncthreads();
        ss[i0] = r0; ss[i1] = r1;
        __syncthreads();
    }
    if (t < NBUCK) {
        int n = cnt[t];
        lscan[t] = ss[t] - n;
        gbase[t] = (n > 0) ? atomicAdd(&gcount[t], n) : 0;
    }
    if (t + 256 < NBUCK) {
        int n = cnt[t + 256];
        lscan[t + 256] = ss[t + 256] - n;
        gbase[t + 256] = (n > 0) ? atomicAdd(&gcount[t + 256], n) : 0;
    }
    if (t == 0) s_total = ss[511];
    __syncthreads();

    #pragma unroll
    for (int j = 0; j < 16; ++j) {
        if (bp[j] >= 0) {
            int b   = bp[j] & 511;
            int rlo = (bp[j] >> 9) & 255;
            int pos = bp[j] >> 17;
            int slot = lscan[b] + pos;
            sbuf[slot]  = make_int2(colr[j] | (rlo << 17), __float_as_int(valr[j]));
            saddr[slot] = b * BCAP + gbase[b] + pos;
        }
    }
    __syncthreads();

    int ce = s_total;
    for (int i = t; i < ce; i += 256)
        epair[saddr[i]] = sbuf[i];
}

// ---------------- Bucket sort: rows within bucket, emit row ranges ------
__global__ __launch_bounds__(256) void bucket_sort(
    const int2* __restrict__ epair, const int* __restrict__ gcount,
    int2* __restrict__ epair2, int2* __restrict__ rowrange)
{
    __shared__ int  cnt[256];
    __shared__ int  off[256];
    __shared__ int  cur[256];
    __shared__ int  ss[256];
    __shared__ int2 sorted[BCAP];

    const int t = threadIdx.x;
    const int b = blockIdx.x;
    const int n = gcount[b];
    const int2* src = epair + (size_t)b * BCAP;

    cnt[t] = 0;
    __syncthreads();
    for (int i = t; i < n; i += 256)
        atomicAdd(&cnt[(src[i].x >> 17) & 255], 1);
    __syncthreads();

    int v = cnt[t];
    ss[t] = v;
    __syncthreads();
    for (int o = 1; o < 256; o <<= 1) {
        int y = (t >= o) ? ss[t - o] : 0;
        __syncthreads();
        ss[t] += y;
        __syncthreads();
    }
    off[t] = ss[t] - v;
    cur[t] = ss[t] - v;
    __syncthreads();

    for (int i = t; i < n; i += 256) {
        int2 p = src[i];
        int slot = atomicAdd(&cur[(p.x >> 17) & 255], 1);
        sorted[slot] = p;
    }
    __syncthreads();

    const int base = b * BCAP;
    for (int i = t; i < n; i += 256)
        epair2[base + i] = sorted[i];
    int row = b * 256 + t;
    if (row < NN)
        rowrange[row] = make_int2(base + off[t], base + off[t] + cnt[t]);
}

// ---------------- Aggregate: one wave per row, 8-deep gather unroll -----
__global__ __launch_bounds__(256) void aggregate(
    const __bf16* __restrict__ tmpb, const int2* __restrict__ rowrange,
    const int2* __restrict__ epair2, float* __restrict__ out)
{
    int wave = (blockIdx.x * 256 + threadIdx.x) >> 6;
    if (wave >= NN) return;
    int lane = threadIdx.x & 63;
    int2 rr = rowrange[wave];
    int beg = rr.x, end = rr.y;

    float ax[4] = {0.f, 0.f, 0.f, 0.f};
    float ay[4] = {0.f, 0.f, 0.f, 0.f};
    int e = beg;
    for (; e + 7 < end; e += 8) {
        int2 p[8];
        #pragma unroll
        for (int k = 0; k < 8; ++k) p[k] = epair2[e + k];
        unsigned u[8];
        #pragma unroll
        for (int k = 0; k < 8; ++k) {
            int col = p[k].x & 0x1FFFF;
            u[k] = *(const unsigned*)(tmpb + (size_t)col * D + lane * 2);
        }
        #pragma unroll
        for (int k = 0; k < 8; ++k) {
            float v = __int_as_float(p[k].y);
            ax[k & 3] += v * __uint_as_float(u[k] << 16);
            ay[k & 3] += v * __uint_as_float(u[k] & 0xffff0000u);
        }
    }
    for (; e < end; ++e) {
        int2 p = epair2[e];
        int col = p.x & 0x1FFFF;
        unsigned u = *(const unsigned*)(tmpb + (size_t)col * D + lane * 2);
        float v = __int_as_float(p.y);
        ax[0] += v * __uint_as_float(u << 16);
        ay[0] += v * __uint_as_float(u & 0xffff0000u);
    }
    float2* o = (float2*)(out + (size_t)wave * D + lane * 2);
    float2 c = *o;
    c.x += (ax[0] + ax[1]) + (ax[2] + ax[3]);
    c.y += (ay[0] + ay[1]) + (ay[2] + ay[3]);
    *o = c;
}

extern "C" void kernel_launch(void* const* d_in, const int* in_sizes, int n_in,
                              void* d_out, int out_size, void* d_ws, size_t ws_size,
                              hipStream_t stream) {
    const float* h     = (const float*)d_in[0];
    const float* eval_ = (const float*)d_in[1];
    const float* Wself = (const float*)d_in[2];
    const float* bself = (const float*)d_in[3];
    const float* Wnb   = (const float*)d_in[4];
    const float* bnb   = (const float*)d_in[5];
    const int*   erow  = (const int*)d_in[6];
    const int*   ecol  = (const int*)d_in[7];
    float* out = (float*)d_out;

    // ws: tmpb 25.6MB | epair 14.4MB | epair2 14.4MB | rowrange 800KB
    //     | wcat 64KB | gcount 1.6KB
    char* p = (char*)d_ws;
    __bf16* tmpb    = (__bf16*)p;   p += (size_t)NN_PAD * D * 2;
    int2*   epair   = (int2*)p;     p += (size_t)NBUCK * BCAP * 8;
    int2*   epair2  = (int2*)p;     p += (size_t)NBUCK * BCAP * 8;
    int2*   rowrange= (int2*)p;     p += (size_t)NN * 8;
    __bf16* wcat    = (__bf16*)p;   p += 256 * 128 * 2;
    int*    gcount  = (int*)p;

    hipMemsetAsync(gcount, 0, NBUCK * 4, stream);

    w_convert<<<128, 256, 0, stream>>>(Wself, Wnb, wcat);
    gemm_mfma<<<NN_PAD / 64, 256, 0, stream>>>(h, wcat, bself, bnb, out, tmpb);
    wc_scatter<<<NCH, 256, 0, stream>>>(erow, ecol, eval_, gcount, epair);
    bucket_sort<<<NBUCK, 256, 0, stream>>>(epair, gcount, epair2, rowrange);
    aggregate<<<(NN * 64) / 256, 256, 0, stream>>>(tmpb, rowrange, epair2, out);
}

// Round 7
// 278.532 us; speedup vs baseline: 5.6211x; 1.0221x over previous
//
#include <hip/hip_runtime.h>

// SAGEConv: out = h@W_self.T + b_self + b_nb + segsum(val * (h@W_nb.T)[col])
// R7: (a) aggregate: 4-deep unroll (8-deep regressed), scalar epair loads via
//     readfirstlane (s_load path), nontemporal out RMW (keep L2 for tmpb
//     gathers), split into 2 dispatches for profiler visibility.
//     (b) gemm: W loaded fp32 + converted in-reg (w_convert kernel deleted).

constexpr int NN = 100000;
constexpr int NE = 1600000;
constexpr int D  = 128;
constexpr int NN_PAD = 100032;             // 64-row padded for GEMM tiles
constexpr int NBUCK  = 391;                // ceil(NN/256) buckets of 256 rows
constexpr int BCAP   = 4608;               // mean 4096 + 8 sigma
constexpr int CHUNK  = 4096;               // edges per wc_scatter workgroup
constexpr int NCH    = (NE + CHUNK - 1) / CHUNK;   // 391

typedef __bf16 bf16x8 __attribute__((ext_vector_type(8)));
typedef float  f32x4  __attribute__((ext_vector_type(4)));
typedef float  f32x2  __attribute__((ext_vector_type(2)));

// ---------------- Dual GEMM: register-resident B, N-split across waves --
// Block: 64 rows x 256 cols. Wave w owns col panel [w*64, w*64+64):
// preload 16 B frags (fp32 load + in-reg bf16 cvt) once; loop 4 M-chunks.
__global__ __launch_bounds__(256) void gemm_mfma(
    const float* __restrict__ h,
    const float* __restrict__ Wself,
    const float* __restrict__ Wnb,
    const float* __restrict__ bself,
    const float* __restrict__ bnb,
    float* __restrict__ out,
    __bf16* __restrict__ tmpb)
{
    const int t    = threadIdx.x;
    const int w    = t >> 6;          // wave id = col panel
    const int lane = t & 63;
    const int l15  = lane & 15;
    const int quad = lane >> 4;

    // Preload B frags from fp32 W: b[ns][kk], frag elem k = quad*8 + kk*32 + j.
    bf16x8 b[4][4];
    #pragma unroll
    for (int ns = 0; ns < 4; ++ns) {
        int wrow = w * 64 + ns * 16 + l15;   // 0..255
        const float* wr = (wrow < D) ? (Wself + (size_t)wrow * D)
                                     : (Wnb + (size_t)(wrow - D) * D);
        #pragma unroll
        for (int kk = 0; kk < 4; ++kk) {
            f32x4 lo = *(const f32x4*)(wr + kk * 32 + quad * 8);
            f32x4 hi = *(const f32x4*)(wr + kk * 32 + quad * 8 + 4);
            bf16x8 bb;
            #pragma unroll
            for (int j = 0; j < 4; ++j) { bb[j] = (__bf16)lo[j]; bb[4 + j] = (__bf16)hi[j]; }
            b[ns][kk] = bb;
        }
    }

    float bias[4];
    #pragma unroll
    for (int ns = 0; ns < 4; ++ns) {
        int col = w * 64 + ns * 16 + l15;
        bias[ns] = (col < D) ? (bself[col] + bnb[col]) : 0.f;
    }

    #pragma unroll
    for (int c = 0; c < 4; ++c) {
        const int m0 = blockIdx.x * 64 + c * 16;
        int arow = m0 + l15;
        if (arow >= NN) arow = NN - 1;
        const float* aptr = h + (size_t)arow * D + quad * 8;

        bf16x8 afr[4];
        #pragma unroll
        for (int kk = 0; kk < 4; ++kk) {
            f32x4 lo = *(const f32x4*)(aptr + kk * 32);
            f32x4 hi = *(const f32x4*)(aptr + kk * 32 + 4);
            bf16x8 a;
            #pragma unroll
            for (int j = 0; j < 4; ++j) { a[j] = (__bf16)lo[j]; a[4 + j] = (__bf16)hi[j]; }
            afr[kk] = a;
        }

        f32x4 acc[4];
        #pragma unroll
        for (int ns = 0; ns < 4; ++ns) acc[ns] = (f32x4){0.f, 0.f, 0.f, 0.f};
        #pragma unroll
        for (int ns = 0; ns < 4; ++ns)
            #pragma unroll
            for (int kk = 0; kk < 4; ++kk)
                acc[ns] = __builtin_amdgcn_mfma_f32_16x16x32_bf16(afr[kk], b[ns][kk], acc[ns], 0, 0, 0);

        if (w < 2) {
            #pragma unroll
            for (int ns = 0; ns < 4; ++ns) {
                int col = w * 64 + ns * 16 + l15;
                #pragma unroll
                for (int i = 0; i < 4; ++i) {
                    int row = m0 + quad * 4 + i;
                    if (row < NN) out[(size_t)row * D + col] = acc[ns][i] + bias[ns];
                }
            }
        } else {
            #pragma unroll
            for (int ns = 0; ns < 4; ++ns) {
                int col = w * 64 + ns * 16 + l15 - D;
                #pragma unroll
                for (int i = 0; i < 4; ++i) {
                    int row = m0 + quad * 4 + i;
                    if (row < NN) tmpb[(size_t)row * D + col] = (__bf16)acc[ns][i];
                }
            }
        }
    }
}

// ---------------- Write-combined bucket scatter (unchanged) -------------
__global__ __launch_bounds__(256) void wc_scatter(
    const int* __restrict__ erow, const int* __restrict__ ecol,
    const float* __restrict__ eval_,
    int* __restrict__ gcount, int2* __restrict__ epair)
{
    __shared__ int  cnt[NBUCK];
    __shared__ int  lscan[NBUCK];
    __shared__ int  gbase[NBUCK];
    __shared__ int  ss[512];
    __shared__ int2 sbuf[CHUNK];
    __shared__ int  saddr[CHUNK];
    __shared__ int  s_total;

    const int t  = threadIdx.x;
    const int c0 = blockIdx.x * CHUNK;

    for (int b = t; b < NBUCK; b += 256) cnt[b] = 0;
    __syncthreads();

    int   bp[16];      // b | rlo<<9 | pos<<17  (or -1 if OOB)
    int   colr[16];
    float valr[16];
    #pragma unroll
    for (int j = 0; j < 16; ++j) {
        int e = c0 + j * 256 + t;
        if (e < NE) {
            int r   = erow[e];
            colr[j] = ecol[e];
            valr[j] = eval_[e];
            int b   = r >> 8;
            int pos = atomicAdd(&cnt[b], 1);
            bp[j]   = b | ((r & 255) << 9) | (pos << 17);
        } else bp[j] = -1;
    }
    __syncthreads();

    ss[t]       = (t < NBUCK)       ? cnt[t]       : 0;
    ss[t + 256] = (t + 256 < NBUCK) ? cnt[t + 256] : 0;
    __syncthreads();
    for (int off = 1; off < 512; off <<= 1) {
        int i0 = t, i1 = t + 256;
        int r0 = ss[i0] + ((i0 >= off) ? ss[i0 - off] : 0);
        int r1 = ss[i1] + ((i1 >= off) ? ss[i1 - off] : 0);
        __syncthreads();
        ss[i0] = r0; ss[i1] = r1;
        __syncthreads();
    }
    if (t < NBUCK) {
        int n = cnt[t];
        lscan[t] = ss[t] - n;
        gbase[t] = (n > 0) ? atomicAdd(&gcount[t], n) : 0;
    }
    if (t + 256 < NBUCK) {
        int n = cnt[t + 256];
        lscan[t + 256] = ss[t + 256] - n;
        gbase[t + 256] = (n > 0) ? atomicAdd(&gcount[t + 256], n) : 0;
    }
    if (t == 0) s_total = ss[511];
    __syncthreads();

    #pragma unroll
    for (int j = 0; j < 16; ++j) {
        if (bp[j] >= 0) {
            int b   = bp[j] & 511;
            int rlo = (bp[j] >> 9) & 255;
            int pos = bp[j] >> 17;
            int slot = lscan[b] + pos;
            sbuf[slot]  = make_int2(colr[j] | (rlo << 17), __float_as_int(valr[j]));
            saddr[slot] = b * BCAP + gbase[b] + pos;
        }
    }
    __syncthreads();

    int ce = s_total;
    for (int i = t; i < ce; i += 256)
        epair[saddr[i]] = sbuf[i];
}

// ---------------- Bucket sort: rows within bucket, emit row ranges ------
__global__ __launch_bounds__(256) void bucket_sort(
    const int2* __restrict__ epair, const int* __restrict__ gcount,
    int2* __restrict__ epair2, int2* __restrict__ rowrange)
{
    __shared__ int  cnt[256];
    __shared__ int  off[256];
    __shared__ int  cur[256];
    __shared__ int  ss[256];
    __shared__ int2 sorted[BCAP];

    const int t = threadIdx.x;
    const int b = blockIdx.x;
    const int n = gcount[b];
    const int2* src = epair + (size_t)b * BCAP;

    cnt[t] = 0;
    __syncthreads();
    for (int i = t; i < n; i += 256)
        atomicAdd(&cnt[(src[i].x >> 17) & 255], 1);
    __syncthreads();

    int v = cnt[t];
    ss[t] = v;
    __syncthreads();
    for (int o = 1; o < 256; o <<= 1) {
        int y = (t >= o) ? ss[t - o] : 0;
        __syncthreads();
        ss[t] += y;
        __syncthreads();
    }
    off[t] = ss[t] - v;
    cur[t] = ss[t] - v;
    __syncthreads();

    for (int i = t; i < n; i += 256) {
        int2 p = src[i];
        int slot = atomicAdd(&cur[(p.x >> 17) & 255], 1);
        sorted[slot] = p;
    }
    __syncthreads();

    const int base = b * BCAP;
    for (int i = t; i < n; i += 256)
        epair2[base + i] = sorted[i];
    int row = b * 256 + t;
    if (row < NN)
        rowrange[row] = make_int2(base + off[t], base + off[t] + cnt[t]);
}

// ---------------- Aggregate: one wave per row, scalar epair loads -------
__global__ __launch_bounds__(256) void aggregate(
    const __bf16* __restrict__ tmpb, const int2* __restrict__ rowrange,
    const int2* __restrict__ epair2, float* __restrict__ out,
    int row0, int nrows)
{
    int wave = row0 + ((blockIdx.x * 256 + threadIdx.x) >> 6);
    if (wave >= row0 + nrows) return;
    int lane = threadIdx.x & 63;
    int2 rr = rowrange[wave];
    int beg = __builtin_amdgcn_readfirstlane(rr.x);   // wave-uniform -> SGPR
    int end = __builtin_amdgcn_readfirstlane(rr.y);   // -> s_load epair path

    float ax[4] = {0.f, 0.f, 0.f, 0.f};
    float ay[4] = {0.f, 0.f, 0.f, 0.f};
    int e = beg;
    for (; e + 3 < end; e += 4) {
        int2 p[4];
        #pragma unroll
        for (int k = 0; k < 4; ++k) p[k] = epair2[e + k];
        #pragma unroll
        for (int k = 0; k < 4; ++k) {
            int col = p[k].x & 0x1FFFF;
            unsigned u = *(const unsigned*)(tmpb + (size_t)col * D + lane * 2);
            float v = __int_as_float(p[k].y);
            ax[k] += v * __uint_as_float(u << 16);
            ay[k] += v * __uint_as_float(u & 0xffff0000u);
        }
    }
    for (; e < end; ++e) {
        int2 p = epair2[e];
        int col = p.x & 0x1FFFF;
        unsigned u = *(const unsigned*)(tmpb + (size_t)col * D + lane * 2);
        float v = __int_as_float(p.y);
        ax[0] += v * __uint_as_float(u << 16);
        ay[0] += v * __uint_as_float(u & 0xffff0000u);
    }
    // Nontemporal RMW of out: don't let the 102MB out-stream evict tmpb in L2.
    f32x2* o = (f32x2*)(out + (size_t)wave * D + lane * 2);
    f32x2 c = __builtin_nontemporal_load(o);
    c.x += (ax[0] + ax[1]) + (ax[2] + ax[3]);
    c.y += (ay[0] + ay[1]) + (ay[2] + ay[3]);
    __builtin_nontemporal_store(c, o);
}

extern "C" void kernel_launch(void* const* d_in, const int* in_sizes, int n_in,
                              void* d_out, int out_size, void* d_ws, size_t ws_size,
                              hipStream_t stream) {
    const float* h     = (const float*)d_in[0];
    const float* eval_ = (const float*)d_in[1];
    const float* Wself = (const float*)d_in[2];
    const float* bself = (const float*)d_in[3];
    const float* Wnb   = (const float*)d_in[4];
    const float* bnb   = (const float*)d_in[5];
    const int*   erow  = (const int*)d_in[6];
    const int*   ecol  = (const int*)d_in[7];
    float* out = (float*)d_out;

    // ws: tmpb 25.6MB | epair 14.4MB | epair2 14.4MB | rowrange 800KB | gcount
    char* p = (char*)d_ws;
    __bf16* tmpb    = (__bf16*)p;   p += (size_t)NN_PAD * D * 2;
    int2*   epair   = (int2*)p;     p += (size_t)NBUCK * BCAP * 8;
    int2*   epair2  = (int2*)p;     p += (size_t)NBUCK * BCAP * 8;
    int2*   rowrange= (int2*)p;     p += (size_t)NN * 8;
    int*    gcount  = (int*)p;

    hipMemsetAsync(gcount, 0, NBUCK * 4, stream);

    gemm_mfma<<<NN_PAD / 64, 256, 0, stream>>>(h, Wself, Wnb, bself, bnb, out, tmpb);
    wc_scatter<<<NCH, 256, 0, stream>>>(erow, ecol, eval_, gcount, epair);
    bucket_sort<<<NBUCK, 256, 0, stream>>>(epair, gcount, epair2, rowrange);
    // Split into two half-row dispatches (visibility + same total work).
    aggregate<<<(50000 * 64) / 256, 256, 0, stream>>>(tmpb, rowrange, epair2, out, 0, 50000);
    aggregate<<<(50000 * 64) / 256, 256, 0, stream>>>(tmpb, rowrange, epair2, out, 50000, 50000);
}

// Round 8
// 264.960 us; speedup vs baseline: 5.9090x; 1.0512x over previous
//
#include <hip/hip_runtime.h>

// SAGEConv: out = h@W_self.T + b_self + b_nb + segsum(val * (h@W_nb.T)[col])
// R8: (a) gemm: LDS-staged bf16 A-tile (m93 shape; was latency-bound on
//     per-wave global A chains, MfmaUtil 3%), (b) wc_scatter/bucket_sort at
//     512 thr (391 blocks were 1.5/CU underparallelized), single-read sort.

constexpr int NN = 100000;
constexpr int NE = 1600000;
constexpr int D  = 128;
constexpr int NBUCK  = 391;                // ceil(NN/256) buckets of 256 rows
constexpr int BCAP   = 4608;               // mean 4096 + 8 sigma
constexpr int CHUNK  = 4096;               // edges per wc_scatter workgroup
constexpr int NCH    = (NE + CHUNK - 1) / CHUNK;   // 391
constexpr int GM     = 64;                 // gemm M-tile
constexpr int NGB    = (NN + GM - 1) / GM; // 1563 gemm blocks
constexpr int LP     = 132;                // LDS row pitch (pad: banks differ per row)

typedef __bf16 bf16x8 __attribute__((ext_vector_type(8)));
typedef float  f32x4  __attribute__((ext_vector_type(4)));
typedef float  f32x2  __attribute__((ext_vector_type(2)));

// ---------------- Dual GEMM: LDS-staged bf16 A, register B --------------
// Block 256 thr = 4 waves; 64 rows x 256 cols. Wave w owns col panel w*64.
__global__ __launch_bounds__(256) void gemm_mfma(
    const float* __restrict__ h,
    const float* __restrict__ Wself,
    const float* __restrict__ Wnb,
    const float* __restrict__ bself,
    const float* __restrict__ bnb,
    float* __restrict__ out,
    __bf16* __restrict__ tmpb)
{
    __shared__ __bf16 hs[GM * LP];    // 16.9 KB
    const int t    = threadIdx.x;
    const int w    = t >> 6;
    const int lane = t & 63;
    const int l15  = lane & 15;
    const int quad = lane >> 4;
    const int row0 = blockIdx.x * GM;

    // Stage: 64x128 fp32 -> bf16 LDS. 32 elems/thread, coalesced.
    #pragma unroll
    for (int it = 0; it < 4; ++it) {
        int idx = it * 2048 + t * 8;
        int r = idx >> 7, c = idx & 127;
        int gr = row0 + r; if (gr >= NN) gr = NN - 1;
        f32x4 lo = *(const f32x4*)(h + (size_t)gr * D + c);
        f32x4 hi = *(const f32x4*)(h + (size_t)gr * D + c + 4);
        bf16x8 v;
        #pragma unroll
        for (int j = 0; j < 4; ++j) { v[j] = (__bf16)lo[j]; v[4 + j] = (__bf16)hi[j]; }
        *(bf16x8*)(hs + r * LP + c) = v;
    }

    // B frags from fp32 W (L2-resident), once per wave.
    bf16x8 b[4][4];
    #pragma unroll
    for (int ns = 0; ns < 4; ++ns) {
        int wrow = w * 64 + ns * 16 + l15;
        const float* wr = (wrow < D) ? (Wself + (size_t)wrow * D)
                                     : (Wnb + (size_t)(wrow - D) * D);
        #pragma unroll
        for (int kk = 0; kk < 4; ++kk) {
            f32x4 lo = *(const f32x4*)(wr + kk * 32 + quad * 8);
            f32x4 hi = *(const f32x4*)(wr + kk * 32 + quad * 8 + 4);
            bf16x8 bb;
            #pragma unroll
            for (int j = 0; j < 4; ++j) { bb[j] = (__bf16)lo[j]; bb[4 + j] = (__bf16)hi[j]; }
            b[ns][kk] = bb;
        }
    }
    float bias[4];
    #pragma unroll
    for (int ns = 0; ns < 4; ++ns) {
        int col = w * 64 + ns * 16 + l15;
        bias[ns] = (col < D) ? (bself[col] + bnb[col]) : 0.f;
    }
    __syncthreads();

    // Compute: 4 M-subtiles x 4 N-subtiles x 4 K-steps.
    f32x4 acc[4][4];
    #pragma unroll
    for (int mi = 0; mi < 4; ++mi)
        #pragma unroll
        for (int ns = 0; ns < 4; ++ns) acc[mi][ns] = (f32x4){0.f, 0.f, 0.f, 0.f};

    #pragma unroll
    for (int mi = 0; mi < 4; ++mi) {
        bf16x8 afr[4];
        #pragma unroll
        for (int kk = 0; kk < 4; ++kk)
            afr[kk] = *(const bf16x8*)(hs + (mi * 16 + l15) * LP + quad * 8 + kk * 32);
        #pragma unroll
        for (int ns = 0; ns < 4; ++ns)
            #pragma unroll
            for (int kk = 0; kk < 4; ++kk)
                acc[mi][ns] = __builtin_amdgcn_mfma_f32_16x16x32_bf16(afr[kk], b[ns][kk], acc[mi][ns], 0, 0, 0);
    }

    // Epilogue.
    #pragma unroll
    for (int mi = 0; mi < 4; ++mi) {
        if (w < 2) {
            #pragma unroll
            for (int ns = 0; ns < 4; ++ns) {
                int col = w * 64 + ns * 16 + l15;
                #pragma unroll
                for (int i = 0; i < 4; ++i) {
                    int row = row0 + mi * 16 + quad * 4 + i;
                    if (row < NN) out[(size_t)row * D + col] = acc[mi][ns][i] + bias[ns];
                }
            }
        } else {
            #pragma unroll
            for (int ns = 0; ns < 4; ++ns) {
                int col = w * 64 + ns * 16 + l15 - D;
                #pragma unroll
                for (int i = 0; i < 4; ++i) {
                    int row = row0 + mi * 16 + quad * 4 + i;
                    if (row < NN) tmpb[(size_t)row * D + col] = (__bf16)acc[mi][ns][i];
                }
            }
        }
    }
}

// ---------------- Write-combined bucket scatter (512 thr) ---------------
__global__ __launch_bounds__(512) void wc_scatter(
    const int* __restrict__ erow, const int* __restrict__ ecol,
    const float* __restrict__ eval_,
    int* __restrict__ gcount, int2* __restrict__ epair)
{
    __shared__ int  cnt[NBUCK];
    __shared__ int  lscan[NBUCK];
    __shared__ int  gbase[NBUCK];
    __shared__ int  ss[512];
    __shared__ int2 sbuf[CHUNK];
    __shared__ int  saddr[CHUNK];
    __shared__ int  s_total;

    const int t  = threadIdx.x;
    const int c0 = blockIdx.x * CHUNK;

    for (int b = t; b < NBUCK; b += 512) cnt[b] = 0;
    __syncthreads();

    int   bp[8];       // b | rlo<<9 | pos<<17  (or -1 if OOB)
    int   colr[8];
    float valr[8];
    #pragma unroll
    for (int j = 0; j < 8; ++j) {
        int e = c0 + j * 512 + t;
        if (e < NE) {
            int r   = erow[e];
            colr[j] = ecol[e];
            valr[j] = eval_[e];
            int b   = r >> 8;
            int pos = atomicAdd(&cnt[b], 1);
            bp[j]   = b | ((r & 255) << 9) | (pos << 17);
        } else bp[j] = -1;
    }
    __syncthreads();

    ss[t] = (t < NBUCK) ? cnt[t] : 0;
    __syncthreads();
    for (int off = 1; off < 512; off <<= 1) {
        int y = (t >= off) ? ss[t - off] : 0;
        __syncthreads();
        ss[t] += y;
        __syncthreads();
    }
    if (t < NBUCK) {
        int n = cnt[t];
        lscan[t] = ss[t] - n;
        gbase[t] = (n > 0) ? atomicAdd(&gcount[t], n) : 0;
    }
    if (t == 0) s_total = ss[511];
    __syncthreads();

    #pragma unroll
    for (int j = 0; j < 8; ++j) {
        if (bp[j] >= 0) {
            int b   = bp[j] & 511;
            int rlo = (bp[j] >> 9) & 255;
            int pos = bp[j] >> 17;
            int slot = lscan[b] + pos;
            sbuf[slot]  = make_int2(colr[j] | (rlo << 17), __float_as_int(valr[j]));
            saddr[slot] = b * BCAP + gbase[b] + pos;
        }
    }
    __syncthreads();

    int ce = s_total;
    for (int i = t; i < ce; i += 512)
        epair[saddr[i]] = sbuf[i];
}

// ---------------- Bucket sort (512 thr, single global read) -------------
__global__ __launch_bounds__(512) void bucket_sort(
    const int2* __restrict__ epair, const int* __restrict__ gcount,
    int2* __restrict__ epair2, int2* __restrict__ rowrange)
{
    __shared__ int  cnt[256];
    __shared__ int  off2[256];
    __shared__ int  cur[256];
    __shared__ int  ss[256];
    __shared__ int2 sorted[BCAP];

    const int t = threadIdx.x;
    const int b = blockIdx.x;
    const int n = gcount[b];
    const int2* src = epair + (size_t)b * BCAP;

    if (t < 256) cnt[t] = 0;
    __syncthreads();

    int2 r[9];
    int  nr = 0;
    for (int i = t; i < n; i += 512) {
        int2 p = src[i];
        r[nr++] = p;
        atomicAdd(&cnt[(p.x >> 17) & 255], 1);
    }
    __syncthreads();

    if (t < 256) ss[t] = cnt[t];
    __syncthreads();
    for (int o = 1; o < 256; o <<= 1) {
        int y = 0;
        if (t < 256 && t >= o) y = ss[t - o];
        __syncthreads();
        if (t < 256) ss[t] += y;
        __syncthreads();
    }
    if (t < 256) {
        int v = cnt[t];
        off2[t] = ss[t] - v;
        cur[t]  = ss[t] - v;
    }
    __syncthreads();

    for (int j = 0; j < nr; ++j) {
        int slot = atomicAdd(&cur[(r[j].x >> 17) & 255], 1);
        sorted[slot] = r[j];
    }
    __syncthreads();

    const int base = b * BCAP;
    for (int i = t; i < n; i += 512)
        epair2[base + i] = sorted[i];
    if (t < 256) {
        int row = b * 256 + t;
        if (row < NN)
            rowrange[row] = make_int2(base + off2[t], base + off2[t] + cnt[t]);
    }
}

// ---------------- Aggregate: one wave per row (unchanged R7) ------------
__global__ __launch_bounds__(256) void aggregate(
    const __bf16* __restrict__ tmpb, const int2* __restrict__ rowrange,
    const int2* __restrict__ epair2, float* __restrict__ out,
    int row0, int nrows)
{
    int wave = row0 + ((blockIdx.x * 256 + threadIdx.x) >> 6);
    if (wave >= row0 + nrows) return;
    int lane = threadIdx.x & 63;
    int2 rr = rowrange[wave];
    int beg = __builtin_amdgcn_readfirstlane(rr.x);
    int end = __builtin_amdgcn_readfirstlane(rr.y);

    float ax[4] = {0.f, 0.f, 0.f, 0.f};
    float ay[4] = {0.f, 0.f, 0.f, 0.f};
    int e = beg;
    for (; e + 3 < end; e += 4) {
        int2 p[4];
        #pragma unroll
        for (int k = 0; k < 4; ++k) p[k] = epair2[e + k];
        #pragma unroll
        for (int k = 0; k < 4; ++k) {
            int col = p[k].x & 0x1FFFF;
            unsigned u = *(const unsigned*)(tmpb + (size_t)col * D + lane * 2);
            float v = __int_as_float(p[k].y);
            ax[k] += v * __uint_as_float(u << 16);
            ay[k] += v * __uint_as_float(u & 0xffff0000u);
        }
    }
    for (; e < end; ++e) {
        int2 p = epair2[e];
        int col = p.x & 0x1FFFF;
        unsigned u = *(const unsigned*)(tmpb + (size_t)col * D + lane * 2);
        float v = __int_as_float(p.y);
        ax[0] += v * __uint_as_float(u << 16);
        ay[0] += v * __uint_as_float(u & 0xffff0000u);
    }
    f32x2* o = (f32x2*)(out + (size_t)wave * D + lane * 2);
    f32x2 c = __builtin_nontemporal_load(o);
    c.x += (ax[0] + ax[1]) + (ax[2] + ax[3]);
    c.y += (ay[0] + ay[1]) + (ay[2] + ay[3]);
    __builtin_nontemporal_store(c, o);
}

extern "C" void kernel_launch(void* const* d_in, const int* in_sizes, int n_in,
                              void* d_out, int out_size, void* d_ws, size_t ws_size,
                              hipStream_t stream) {
    const float* h     = (const float*)d_in[0];
    const float* eval_ = (const float*)d_in[1];
    const float* Wself = (const float*)d_in[2];
    const float* bself = (const float*)d_in[3];
    const float* Wnb   = (const float*)d_in[4];
    const float* bnb   = (const float*)d_in[5];
    const int*   erow  = (const int*)d_in[6];
    const int*   ecol  = (const int*)d_in[7];
    float* out = (float*)d_out;

    char* p = (char*)d_ws;
    __bf16* tmpb    = (__bf16*)p;   p += (size_t)NGB * GM * D * 2;
    int2*   epair   = (int2*)p;     p += (size_t)NBUCK * BCAP * 8;
    int2*   epair2  = (int2*)p;     p += (size_t)NBUCK * BCAP * 8;
    int2*   rowrange= (int2*)p;     p += (size_t)NN * 8;
    int*    gcount  = (int*)p;

    hipMemsetAsync(gcount, 0, NBUCK * 4, stream);

    gemm_mfma<<<NGB, 256, 0, stream>>>(h, Wself, Wnb, bself, bnb, out, tmpb);
    wc_scatter<<<NCH, 512, 0, stream>>>(erow, ecol, eval_, gcount, epair);
    bucket_sort<<<NBUCK, 512, 0, stream>>>(epair, gcount, epair2, rowrange);
    aggregate<<<(50000 * 64) / 256, 256, 0, stream>>>(tmpb, rowrange, epair2, out, 0, 50000);
    aggregate<<<(50000 * 64) / 256, 256, 0, stream>>>(tmpb, rowrange, epair2, out, 50000, 50000);
}

// Round 9
// 263.121 us; speedup vs baseline: 5.9503x; 1.0070x over previous
//
#include <hip/hip_runtime.h>

// SAGEConv: out = h@W_self.T + b_self + b_nb + segsum(val * (h@W_nb.T)[col])
// R9: (a) gemm: swapped MFMA operands -> C-layout transposed -> x4-packed,
//     fully coalesced epilogue (16 dwordx4 stores vs 64 dword); 2 tiles/block
//     with LDS double-buffer + register prefetch (782 blocks).
//     (b) bucket geometry 500x200 + CHUNK 2048 -> balanced grids (782/500).

constexpr int NN = 100000;
constexpr int NE = 1600000;
constexpr int D  = 128;
constexpr int NBUCK  = 500;                // buckets of BROWS rows
constexpr int BROWS  = 200;                // 500*200 = 100000 exactly
constexpr int BCAP   = 3584;               // mean 3200 + ~7 sigma
constexpr int CHUNK  = 2048;               // edges per wc_scatter workgroup
constexpr int NCH    = (NE + CHUNK - 1) / CHUNK;   // 782
constexpr int GM     = 64;                 // gemm M-tile rows
constexpr int TPB    = 2;                  // tiles per gemm block
constexpr int NGB    = (NN + GM * TPB - 1) / (GM * TPB);  // 782
constexpr int LP     = 132;                // LDS bf16 pitch (2-way = free)

typedef __bf16 bf16x8 __attribute__((ext_vector_type(8)));
typedef float  f32x4  __attribute__((ext_vector_type(4)));
typedef float  f32x2  __attribute__((ext_vector_type(2)));
typedef unsigned short u16x4 __attribute__((ext_vector_type(4)));

// ---------------- Dual GEMM ----------------
__global__ __launch_bounds__(256) void gemm_mfma(
    const float* __restrict__ h,
    const float* __restrict__ Wself,
    const float* __restrict__ Wnb,
    const float* __restrict__ bself,
    const float* __restrict__ bnb,
    float* __restrict__ out,
    __bf16* __restrict__ tmpb)
{
    __shared__ __bf16 hs[2][GM * LP];   // 2 x 16.9 KB
    const int t    = threadIdx.x;
    const int w    = t >> 6;
    const int lane = t & 63;
    const int l15  = lane & 15;
    const int quad = lane >> 4;
    const int base_row = blockIdx.x * GM * TPB;

    // W frags (A operand): frag[ns][kk], m = w*64+ns*16+l15, k = quad*8+kk*32+j.
    bf16x8 wf[4][4];
    #pragma unroll
    for (int ns = 0; ns < 4; ++ns) {
        int wrow = w * 64 + ns * 16 + l15;
        const float* wr = (wrow < D) ? (Wself + (size_t)wrow * D)
                                     : (Wnb + (size_t)(wrow - D) * D);
        #pragma unroll
        for (int kk = 0; kk < 4; ++kk) {
            f32x4 lo = *(const f32x4*)(wr + kk * 32 + quad * 8);
            f32x4 hi = *(const f32x4*)(wr + kk * 32 + quad * 8 + 4);
            bf16x8 bb;
            #pragma unroll
            for (int j = 0; j < 4; ++j) { bb[j] = (__bf16)lo[j]; bb[4 + j] = (__bf16)hi[j]; }
            wf[ns][kk] = bb;
        }
    }
    // Bias vectors (cols ns*16+quad*4 .. +3), only used by waves 0,1.
    f32x4 biasv[4];
    #pragma unroll
    for (int ns = 0; ns < 4; ++ns) {
        int col = w * 64 + ns * 16 + quad * 4;
        if (col < D) {
            f32x4 b1 = *(const f32x4*)(bself + col);
            f32x4 b2 = *(const f32x4*)(bnb + col);
            biasv[ns] = b1 + b2;
        } else biasv[ns] = (f32x4){0.f, 0.f, 0.f, 0.f};
    }

    // Stage tile 0 into hs[0].
    {
        #pragma unroll
        for (int it = 0; it < 4; ++it) {
            int idx = it * 2048 + t * 8;
            int r = idx >> 7, c = idx & 127;
            int gr = base_row + r; if (gr >= NN) gr = NN - 1;
            f32x4 lo = *(const f32x4*)(h + (size_t)gr * D + c);
            f32x4 hi = *(const f32x4*)(h + (size_t)gr * D + c + 4);
            bf16x8 v;
            #pragma unroll
            for (int j = 0; j < 4; ++j) { v[j] = (__bf16)lo[j]; v[4 + j] = (__bf16)hi[j]; }
            *(bf16x8*)(&hs[0][r * LP + c]) = v;
        }
    }
    __syncthreads();

    #pragma unroll
    for (int tt = 0; tt < TPB; ++tt) {
        const int row0 = base_row + tt * GM;

        // Prefetch next tile's h into registers (overlaps compute below).
        f32x4 pf[8];
        if (tt + 1 < TPB) {
            #pragma unroll
            for (int it = 0; it < 4; ++it) {
                int idx = it * 2048 + t * 8;
                int r = idx >> 7, c = idx & 127;
                int gr = base_row + GM + r; if (gr >= NN) gr = NN - 1;
                pf[it * 2]     = *(const f32x4*)(h + (size_t)gr * D + c);
                pf[it * 2 + 1] = *(const f32x4*)(h + (size_t)gr * D + c + 4);
            }
        }

        // Compute: acc[mi][ns]; C-layout (swapped operands):
        //   C col(lane&15) = out-row = mi*16+l15 ; C row(quad*4+reg) = out-col.
        f32x4 acc[4][4];
        #pragma unroll
        for (int mi = 0; mi < 4; ++mi)
            #pragma unroll
            for (int ns = 0; ns < 4; ++ns) acc[mi][ns] = (f32x4){0.f, 0.f, 0.f, 0.f};

        #pragma unroll
        for (int mi = 0; mi < 4; ++mi) {
            bf16x8 hf[4];
            #pragma unroll
            for (int kk = 0; kk < 4; ++kk)
                hf[kk] = *(const bf16x8*)(&hs[tt & 1][(mi * 16 + l15) * LP + quad * 8 + kk * 32]);
            #pragma unroll
            for (int ns = 0; ns < 4; ++ns)
                #pragma unroll
                for (int kk = 0; kk < 4; ++kk)
                    acc[mi][ns] = __builtin_amdgcn_mfma_f32_16x16x32_bf16(wf[ns][kk], hf[kk], acc[mi][ns], 0, 0, 0);
        }

        // Write prefetched tile into the other LDS buffer.
        if (tt + 1 < TPB) {
            #pragma unroll
            for (int it = 0; it < 4; ++it) {
                int idx = it * 2048 + t * 8;
                int r = idx >> 7, c = idx & 127;
                bf16x8 v;
                #pragma unroll
                for (int j = 0; j < 4; ++j) {
                    v[j]     = (__bf16)pf[it * 2][j];
                    v[4 + j] = (__bf16)pf[it * 2 + 1][j];
                }
                *(bf16x8*)(&hs[(tt + 1) & 1][r * LP + c]) = v;
            }
            __syncthreads();
        }

        // Epilogue: packed stores, overlaps next tile's compute.
        #pragma unroll
        for (int mi = 0; mi < 4; ++mi) {
            int row = row0 + mi * 16 + l15;
            if (row < NN) {
                if (w < 2) {
                    #pragma unroll
                    for (int ns = 0; ns < 4; ++ns) {
                        int col = w * 64 + ns * 16 + quad * 4;
                        *(f32x4*)(out + (size_t)row * D + col) = acc[mi][ns] + biasv[ns];
                    }
                } else {
                    #pragma unroll
                    for (int ns = 0; ns < 4; ++ns) {
                        int col = (w - 2) * 64 + ns * 16 + quad * 4;
                        u16x4 v;
                        #pragma unroll
                        for (int i = 0; i < 4; ++i) {
                            __bf16 b = (__bf16)acc[mi][ns][i];
                            v[i] = *(unsigned short*)&b;
                        }
                        *(u16x4*)(tmpb + (size_t)row * D + col) = v;
                    }
                }
            }
        }
    }
}

// ---------------- Write-combined bucket scatter (500 bins, CHUNK 2048) --
__global__ __launch_bounds__(256) void wc_scatter(
    const int* __restrict__ erow, const int* __restrict__ ecol,
    const float* __restrict__ eval_,
    int* __restrict__ gcount, int2* __restrict__ epair)
{
    __shared__ int  cnt[NBUCK];
    __shared__ int  lscan[NBUCK];
    __shared__ int  gbase[NBUCK];
    __shared__ int  ss[512];
    __shared__ int2 sbuf[CHUNK];
    __shared__ int  saddr[CHUNK];
    __shared__ int  s_total;

    const int t  = threadIdx.x;
    const int c0 = blockIdx.x * CHUNK;

    for (int b = t; b < NBUCK; b += 256) cnt[b] = 0;
    __syncthreads();

    int   bp[8];       // b | rlo<<9 | pos<<17  (or -1 if OOB)
    int   colr[8];
    float valr[8];
    #pragma unroll
    for (int j = 0; j < 8; ++j) {
        int e = c0 + j * 256 + t;
        if (e < NE) {
            int r   = erow[e];
            colr[j] = ecol[e];
            valr[j] = eval_[e];
            int b   = r / BROWS;
            int rlo = r - b * BROWS;
            int pos = atomicAdd(&cnt[b], 1);
            bp[j]   = b | (rlo << 9) | (pos << 17);
        } else bp[j] = -1;
    }
    __syncthreads();

    // Scan 512 slots with 256 threads (2/thread).
    ss[t]       = (t < NBUCK)       ? cnt[t]       : 0;
    ss[t + 256] = (t + 256 < NBUCK) ? cnt[t + 256] : 0;
    __syncthreads();
    for (int off = 1; off < 512; off <<= 1) {
        int i0 = t, i1 = t + 256;
        int r0 = ss[i0] + ((i0 >= off) ? ss[i0 - off] : 0);
        int r1 = ss[i1] + ((i1 >= off) ? ss[i1 - off] : 0);
        __syncthreads();
        ss[i0] = r0; ss[i1] = r1;
        __syncthreads();
    }
    if (t < NBUCK) {
        int n = cnt[t];
        lscan[t] = ss[t] - n;
        gbase[t] = (n > 0) ? atomicAdd(&gcount[t], n) : 0;
    }
    if (t + 256 < NBUCK) {
        int n = cnt[t + 256];
        lscan[t + 256] = ss[t + 256] - n;
        gbase[t + 256] = (n > 0) ? atomicAdd(&gcount[t + 256], n) : 0;
    }
    if (t == 0) s_total = ss[511];
    __syncthreads();

    #pragma unroll
    for (int j = 0; j < 8; ++j) {
        if (bp[j] >= 0) {
            int b   = bp[j] & 511;
            int rlo = (bp[j] >> 9) & 255;
            int pos = bp[j] >> 17;
            int slot = lscan[b] + pos;
            sbuf[slot]  = make_int2(colr[j] | (rlo << 17), __float_as_int(valr[j]));
            saddr[slot] = b * BCAP + gbase[b] + pos;
        }
    }
    __syncthreads();

    int ce = s_total;
    for (int i = t; i < ce; i += 256)
        epair[saddr[i]] = sbuf[i];
}

// ---------------- Bucket sort (500 blocks, 512 thr) ---------------------
__global__ __launch_bounds__(512) void bucket_sort(
    const int2* __restrict__ epair, const int* __restrict__ gcount,
    int2* __restrict__ epair2, int2* __restrict__ rowrange)
{
    __shared__ int  cnt[BROWS];
    __shared__ int  off2[BROWS];
    __shared__ int  cur[BROWS];
    __shared__ int  ss[256];
    __shared__ int2 sorted[BCAP];

    const int t = threadIdx.x;
    const int b = blockIdx.x;
    const int n = gcount[b];
    const int2* src = epair + (size_t)b * BCAP;

    if (t < BROWS) cnt[t] = 0;
    __syncthreads();

    int2 r[8];
    int  nr = 0;
    for (int i = t; i < n; i += 512) {
        int2 p = src[i];
        r[nr++] = p;
        atomicAdd(&cnt[(p.x >> 17) & 255], 1);
    }
    __syncthreads();

    if (t < 256) ss[t] = (t < BROWS) ? cnt[t] : 0;
    __syncthreads();
    for (int o = 1; o < 256; o <<= 1) {
        int y = 0;
        if (t < 256 && t >= o) y = ss[t - o];
        __syncthreads();
        if (t < 256) ss[t] += y;
        __syncthreads();
    }
    if (t < BROWS) {
        int v = cnt[t];
        off2[t] = ss[t] - v;
        cur[t]  = ss[t] - v;
    }
    __syncthreads();

    for (int j = 0; j < nr; ++j) {
        int slot = atomicAdd(&cur[(r[j].x >> 17) & 255], 1);
        sorted[slot] = r[j];
    }
    __syncthreads();

    const int base = b * BCAP;
    for (int i = t; i < n; i += 512)
        epair2[base + i] = sorted[i];
    if (t < BROWS) {
        int row = b * BROWS + t;
        if (row < NN)
            rowrange[row] = make_int2(base + off2[t], base + off2[t] + cnt[t]);
    }
}

// ---------------- Aggregate: one wave per row (unchanged) ---------------
__global__ __launch_bounds__(256) void aggregate(
    const __bf16* __restrict__ tmpb, const int2* __restrict__ rowrange,
    const int2* __restrict__ epair2, float* __restrict__ out,
    int row0, int nrows)
{
    int wave = row0 + ((blockIdx.x * 256 + threadIdx.x) >> 6);
    if (wave >= row0 + nrows) return;
    int lane = threadIdx.x & 63;
    int2 rr = rowrange[wave];
    int beg = __builtin_amdgcn_readfirstlane(rr.x);
    int end = __builtin_amdgcn_readfirstlane(rr.y);

    float ax[4] = {0.f, 0.f, 0.f, 0.f};
    float ay[4] = {0.f, 0.f, 0.f, 0.f};
    int e = beg;
    for (; e + 3 < end; e += 4) {
        int2 p[4];
        #pragma unroll
        for (int k = 0; k < 4; ++k) p[k] = epair2[e + k];
        #pragma unroll
        for (int k = 0; k < 4; ++k) {
            int col = p[k].x & 0x1FFFF;
            unsigned u = *(const unsigned*)(tmpb + (size_t)col * D + lane * 2);
            float v = __int_as_float(p[k].y);
            ax[k] += v * __uint_as_float(u << 16);
            ay[k] += v * __uint_as_float(u & 0xffff0000u);
        }
    }
    for (; e < end; ++e) {
        int2 p = epair2[e];
        int col = p.x & 0x1FFFF;
        unsigned u = *(const unsigned*)(tmpb + (size_t)col * D + lane * 2);
        float v = __int_as_float(p.y);
        ax[0] += v * __uint_as_float(u << 16);
        ay[0] += v * __uint_as_float(u & 0xffff0000u);
    }
    f32x2* o = (f32x2*)(out + (size_t)wave * D + lane * 2);
    f32x2 c = __builtin_nontemporal_load(o);
    c.x += (ax[0] + ax[1]) + (ax[2] + ax[3]);
    c.y += (ay[0] + ay[1]) + (ay[2] + ay[3]);
    __builtin_nontemporal_store(c, o);
}

extern "C" void kernel_launch(void* const* d_in, const int* in_sizes, int n_in,
                              void* d_out, int out_size, void* d_ws, size_t ws_size,
                              hipStream_t stream) {
    const float* h     = (const float*)d_in[0];
    const float* eval_ = (const float*)d_in[1];
    const float* Wself = (const float*)d_in[2];
    const float* bself = (const float*)d_in[3];
    const float* Wnb   = (const float*)d_in[4];
    const float* bnb   = (const float*)d_in[5];
    const int*   erow  = (const int*)d_in[6];
    const int*   ecol  = (const int*)d_in[7];
    float* out = (float*)d_out;

    // ws: tmpb 25.6MB | epair 14.3MB | epair2 14.3MB | rowrange 800KB | gcount
    char* p = (char*)d_ws;
    __bf16* tmpb    = (__bf16*)p;   p += (size_t)(NGB * GM * TPB) * D * 2;
    int2*   epair   = (int2*)p;     p += (size_t)NBUCK * BCAP * 8;
    int2*   epair2  = (int2*)p;     p += (size_t)NBUCK * BCAP * 8;
    int2*   rowrange= (int2*)p;     p += (size_t)NN * 8;
    int*    gcount  = (int*)p;

    hipMemsetAsync(gcount, 0, NBUCK * 4, stream);

    gemm_mfma<<<NGB, 256, 0, stream>>>(h, Wself, Wnb, bself, bnb, out, tmpb);
    wc_scatter<<<NCH, 256, 0, stream>>>(erow, ecol, eval_, gcount, epair);
    bucket_sort<<<NBUCK, 512, 0, stream>>>(epair, gcount, epair2, rowrange);
    aggregate<<<(50000 * 64) / 256, 256, 0, stream>>>(tmpb, rowrange, epair2, out, 0, 50000);
    aggregate<<<(50000 * 64) / 256, 256, 0, stream>>>(tmpb, rowrange, epair2, out, 50000, 50000);
}